// Round 10
// baseline (252.319 us; speedup 1.0000x reference)
//
#include <hip/hip_runtime.h>

// SelfAttention: B=4 S=2048 D=1024 H=16 HD=64, causal, fp32 in/out, bf16 MFMA compute.
// R18->R19: attn l-accumulation moved from VALU to MFMA (ones-column trick).
// R18 verdict: attn is VALU-bound (halving LDS reads/barriers gave +2%; VALUBusy 58
// followed dur, MfmaUtil 29 idle headroom). Change: l = mfma(pf, ones, l) -- B=ones
// makes each D column the P-row-sum, and D rows are already o-indexed (q=quad*4+r),
// so: per tile-step per group delete 12 psum adds + 2 shfl_xor; delete the 16
// epilogue l-transpose shfls entirely. +8 MFMA/tile-step on the 29%-utilized matrix
// pipe. Denominator uses the same bf16-rounded P as the numerator (errors correlate).
// Defer-rescale multiplies l_acc[r] by the same at[r] as o. GEMMs/cast/transpose
// byte-identical to R18 (control).

typedef __attribute__((ext_vector_type(8))) short short8_t;
typedef __attribute__((ext_vector_type(4))) short short4_t;
typedef __attribute__((ext_vector_type(4))) float float4_t;

constexpr int Bz = 4, Sq = 2048, Dm = 1024, NH = 16, HD = 64;

#define GLOAD_LDS16(g, l)                                                      \
  __builtin_amdgcn_global_load_lds(                                            \
      (const __attribute__((address_space(1))) unsigned int*)(g),              \
      (__attribute__((address_space(3))) unsigned int*)(l), 16, 0, 0)

__device__ __forceinline__ unsigned short f2bf(float f) {
  unsigned u = __builtin_bit_cast(unsigned, f);
  u += 0x7fffu + ((u >> 16) & 1u);
  return (unsigned short)(u >> 16);
}

__device__ __forceinline__ float exp2_fast(float x) {
#if __has_builtin(__builtin_amdgcn_exp2f)
  return __builtin_amdgcn_exp2f(x);
#else
  return exp2f(x);
#endif
}

__device__ __forceinline__ float m3(float a, float b, float c) {
  return fmaxf(fmaxf(a, b), c);  // clang emits v_max3_f32
}

__global__ __launch_bounds__(256) void cast_x_kernel(const float* __restrict__ x,
                                                     unsigned short* __restrict__ xb) {
  size_t i = (size_t)blockIdx.x * 256 + threadIdx.x;
  float4 v = ((const float4*)x)[i];
  ushort4 o;
  o.x = f2bf(v.x); o.y = f2bf(v.y); o.z = f2bf(v.z); o.w = f2bf(v.w);
  ((ushort4*)xb)[i] = o;
}

// All four W [K=1024][N=1024] fp32 -> WT [N][K] bf16 in one launch. grid (16,16,4).
__global__ __launch_bounds__(256) void transpose_w_kernel(
    const float* __restrict__ Wq, const float* __restrict__ Wk,
    const float* __restrict__ Wv, const float* __restrict__ Wo,
    unsigned short* __restrict__ wqT, unsigned short* __restrict__ wkT,
    unsigned short* __restrict__ wvT, unsigned short* __restrict__ woT) {
  __shared__ float tile[64][65];
  int zz = blockIdx.z;
  const float* W = zz == 0 ? Wq : (zz == 1 ? Wk : (zz == 2 ? Wv : Wo));
  unsigned short* WT = zz == 0 ? wqT : (zz == 1 ? wkT : (zz == 2 ? wvT : woT));
  int n0 = blockIdx.x * 64, k0 = blockIdx.y * 64;
  int tx = threadIdx.x & 63, ty = threadIdx.x >> 6;
#pragma unroll
  for (int i = 0; i < 16; ++i) {
    int r = i * 4 + ty;
    tile[r][tx] = W[(size_t)(k0 + r) * Dm + n0 + tx];
  }
  __syncthreads();
#pragma unroll
  for (int i = 0; i < 16; ++i) {
    int r = i * 4 + ty;
    WT[(size_t)(n0 + r) * Dm + k0 + tx] = f2bf(tile[tx][r]);
  }
}

// ---------------- 128x256 8-wave phase-pipelined mainloop ----------------
#define SBAR do { __builtin_amdgcn_sched_barrier(0); __builtin_amdgcn_s_barrier(); } while (0)
#define VMW(n_) asm volatile("s_waitcnt vmcnt(" #n_ ")" ::: "memory")

#define STGA2(buf_, kt_) do {                                                  \
  GLOAD_LDS16(gA + (size_t)lrow * Dm + (kt_) * 64 + csA,                       \
              smA + (buf_) * 8192 + tid * 8);                                  \
  GLOAD_LDS16(gA + (size_t)(lrow + 64) * Dm + (kt_) * 64 + csA,                \
              smA + (buf_) * 8192 + 4096 + tid * 8);                           \
} while (0)
#define STGB4(buf_, kt_) do {                                                  \
  GLOAD_LDS16(gB + (size_t)lrow * Dm + (kt_) * 64 + csA,                       \
              smB + (buf_) * 16384 + tid * 8);                                 \
  GLOAD_LDS16(gB + (size_t)(lrow + 64) * Dm + (kt_) * 64 + csA,                \
              smB + (buf_) * 16384 + 4096 + tid * 8);                          \
  GLOAD_LDS16(gB + (size_t)(lrow + 128) * Dm + (kt_) * 64 + csA,               \
              smB + (buf_) * 16384 + 8192 + tid * 8);                          \
  GLOAD_LDS16(gB + (size_t)(lrow + 192) * Dm + (kt_) * 64 + csA,               \
              smB + (buf_) * 16384 + 12288 + tid * 8);                         \
} while (0)
#define LDA8(buf_) do {                                                        \
  _Pragma("unroll") for (int i_ = 0; i_ < 4; ++i_) {                           \
    const unsigned short* p_ = smA + (buf_) * 8192 + aoff + i_ * 1024;         \
    a[i_][0] = *(const short8_t*)(p_ + csw0);                                  \
    a[i_][1] = *(const short8_t*)(p_ + csw1);                                  \
  }                                                                            \
} while (0)
#define LDB4(dst_, buf_, jh_) do {                                             \
  _Pragma("unroll") for (int j_ = 0; j_ < 2; ++j_) {                           \
    const unsigned short* p_ =                                                 \
        smB + (buf_) * 16384 + boff + ((jh_) * 2 + j_) * 1024;                 \
    dst_[j_][0] = *(const short8_t*)(p_ + csw0);                               \
    dst_[j_][1] = *(const short8_t*)(p_ + csw1);                               \
  }                                                                            \
} while (0)
#define MF16(breg_, joff_) do {                                                \
  __builtin_amdgcn_s_setprio(1);                                               \
  _Pragma("unroll") for (int i_ = 0; i_ < 4; ++i_)                             \
  _Pragma("unroll") for (int j_ = 0; j_ < 2; ++j_) {                           \
    acc[i_][(joff_) + j_] = __builtin_amdgcn_mfma_f32_16x16x32_bf16(           \
        a[i_][0], breg_[j_][0], acc[i_][(joff_) + j_], 0, 0, 0);               \
    acc[i_][(joff_) + j_] = __builtin_amdgcn_mfma_f32_16x16x32_bf16(           \
        a[i_][1], breg_[j_][1], acc[i_][(joff_) + j_], 0, 0, 0);               \
  }                                                                            \
  __builtin_amdgcn_s_setprio(0);                                               \
} while (0)

__device__ __forceinline__ void gemm128x256_mainloop(
    const unsigned short* __restrict__ A, const unsigned short* __restrict__ BT,
    int m0, int n0, unsigned short* smA, unsigned short* smB, float4_t acc[4][4]) {
  const int tid = threadIdx.x;
  const int lane = tid & 63, lr = lane & 15, quad = lane >> 4;
  const int wid = tid >> 6, wm = wid >> 2, wn = wid & 3;
  const int aoff = (wm * 64 + lr) * 64;
  const int boff = (wn * 64 + lr) * 64;
  const int csw0 = (quad ^ (lr & 7)) * 8;
  const int csw1 = csw0 ^ 32;
  const int lrow = tid >> 3;
  const int csA = ((tid & 7) ^ (lrow & 7)) * 8;
  const unsigned short* gA = A + (size_t)m0 * Dm;
  const unsigned short* gB = BT + (size_t)n0 * Dm;

  short8_t a[4][2], bA[2][2], bB[2][2];

  STGA2(0, 0); STGB4(0, 0); STGA2(1, 1);
  VMW(2); SBAR;

#pragma unroll 1
  for (int T = 0; T < 7; ++T) {
    const int t1 = 2 * T + 1, t2 = 2 * T + 2, t3 = 2 * T + 3;
    LDA8(0); LDB4(bA, 0, 0); STGB4(1, t1); SBAR; MF16(bA, 0); SBAR;
    LDB4(bB, 0, 1); STGA2(0, t2); SBAR; MF16(bB, 2); VMW(2); SBAR;
    LDA8(1); LDB4(bA, 1, 0); STGB4(0, t2); SBAR; MF16(bA, 0); SBAR;
    LDB4(bB, 1, 1); STGA2(1, t3); SBAR; MF16(bB, 2); VMW(2); SBAR;
  }
  LDA8(0); LDB4(bA, 0, 0); STGB4(1, 15); SBAR; MF16(bA, 0); SBAR;
  LDB4(bB, 0, 1); SBAR; MF16(bB, 2); VMW(0); SBAR;
  LDA8(1); LDB4(bA, 1, 0); SBAR; MF16(bA, 0); SBAR;
  LDB4(bB, 1, 1); SBAR; MF16(bB, 2);
}

// QKV projections, 128x256 tiles. grid 768 linear (3 exact rounds), XCD cpx=96.
__global__ __launch_bounds__(512, 2) void gemm_qkv_kernel(
    const unsigned short* __restrict__ xb,
    const unsigned short* __restrict__ wqT, const unsigned short* __restrict__ wkT,
    const unsigned short* __restrict__ wvT,
    unsigned short* __restrict__ qb, unsigned short* __restrict__ kb,
    unsigned short* __restrict__ vt) {
  __shared__ unsigned short smA[2 * 8192];
  __shared__ unsigned short smB[2 * 16384];
  int lin = (int)blockIdx.x;
  int logical = (lin & 7) * 96 + (lin >> 3);
  int bx = logical & 3;
  int by = (logical >> 2) & 63;
  int bz = logical >> 8;
  const unsigned short* WT = bz == 0 ? wqT : (bz == 1 ? wkT : wvT);
  unsigned short* outb = bz == 0 ? qb : (bz == 1 ? kb : vt);
  bool isV = bz == 2;
  float qscale = (bz == 0) ? 0.18033688011112042f : 1.0f;
  int m0 = by * 128, n0 = bx * 256;
  float4_t z = {0.f, 0.f, 0.f, 0.f};
  float4_t acc[4][4];
#pragma unroll
  for (int i = 0; i < 4; ++i)
#pragma unroll
    for (int j = 0; j < 4; ++j) acc[i][j] = z;
  gemm128x256_mainloop(xb, WT, m0, n0, smA, smB, acc);

  const int lane = threadIdx.x & 63, lr = lane & 15, quad = lane >> 4;
  const int wid = threadIdx.x >> 6, wm = wid >> 2, wn = wid & 3;
  const int mb = m0 + wm * 64 + quad * 4;
  const int nb = n0 + wn * 64 + lr;
  if (isV) {
#pragma unroll
    for (int ai = 0; ai < 4; ++ai)
#pragma unroll
      for (int bj = 0; bj < 4; ++bj) {
        int m = mb + ai * 16;
        int n = nb + bj * 16;
        int b = m >> 11, s = m & (Sq - 1);
        int h = n >> 6, hd = n & (HD - 1);
        ushort4 pk;
        pk.x = f2bf(acc[ai][bj][0]); pk.y = f2bf(acc[ai][bj][1]);
        pk.z = f2bf(acc[ai][bj][2]); pk.w = f2bf(acc[ai][bj][3]);
        *(ushort4*)(outb + (((size_t)b * NH + h) * HD + hd) * Sq + s) = pk;
      }
  } else {
#pragma unroll
    for (int ai = 0; ai < 4; ++ai)
#pragma unroll
      for (int bj = 0; bj < 4; ++bj)
#pragma unroll
        for (int r = 0; r < 4; ++r) {
          int m = mb + ai * 16 + r;
          int n = nb + bj * 16;
          int b = m >> 11, s = m & (Sq - 1);
          int h = n >> 6, hd = n & (HD - 1);
          outb[(((size_t)b * NH + h) * Sq + s) * HD + hd] = f2bf(acc[ai][bj][r] * qscale);
        }
  }
}

// Output projection: ao_bf16 [8192,1024] @ Wo -> fp32. grid 256 (1 exact round), cpx=32.
__global__ __launch_bounds__(512, 2) void gemm_out_kernel(
    const unsigned short* __restrict__ ao, const unsigned short* __restrict__ woT,
    float* __restrict__ out) {
  __shared__ unsigned short smA[2 * 8192];
  __shared__ unsigned short smB[2 * 16384];
  int lin = (int)blockIdx.x;
  int logical = (lin & 7) * 32 + (lin >> 3);
  int bx = logical & 3;
  int by = logical >> 2;
  int m0 = by * 128, n0 = bx * 256;
  float4_t z = {0.f, 0.f, 0.f, 0.f};
  float4_t acc[4][4];
#pragma unroll
  for (int i = 0; i < 4; ++i)
#pragma unroll
    for (int j = 0; j < 4; ++j) acc[i][j] = z;
  gemm128x256_mainloop(ao, woT, m0, n0, smA, smB, acc);

  const int lane = threadIdx.x & 63, lr = lane & 15, quad = lane >> 4;
  const int wid = threadIdx.x >> 6, wm = wid >> 2, wn = wid & 3;
  const int mb = m0 + wm * 64 + quad * 4;
  const int nb = n0 + wn * 64 + lr;
#pragma unroll
  for (int ai = 0; ai < 4; ++ai)
#pragma unroll
    for (int bj = 0; bj < 4; ++bj)
#pragma unroll
      for (int r = 0; r < 4; ++r) {
        int m = mb + ai * 16 + r;
        int n = nb + bj * 16;
        out[(size_t)m * Dm + n] = acc[ai][bj][r];
      }
}

// Flash attention — grid (B*H, 16), 128-row q-tile per block, 4 waves x 32 q-rows.
// K/V fragments shared by both 16-row groups per wave. l accumulated via
// mfma(pf, ones) -> l arrives o-indexed (q=quad*4+r), no psum adds / no l shfls.
__global__ __launch_bounds__(256) void attn_kernel(
    const unsigned short* __restrict__ qbuf, const unsigned short* __restrict__ kbuf,
    const unsigned short* __restrict__ vtbuf, unsigned short* __restrict__ ao) {
  __shared__ unsigned short lk[2 * 64 * 64];
  __shared__ unsigned short lv[2 * 64 * 64];
  int tid = threadIdx.x;
  int bh = blockIdx.x;
  int ti = 15 - (int)blockIdx.y;
  int wave = tid >> 6, lane = tid & 63;
  int lcol = lane & 15, quad = lane >> 4;
  int lc7 = lcol & 7;
  const unsigned short* Q = qbuf + (size_t)bh * Sq * HD;
  const unsigned short* K = kbuf + (size_t)bh * Sq * HD;
  const unsigned short* Vt = vtbuf + (size_t)bh * HD * Sq;
  int b = bh >> 4, h = bh & 15;
  float4_t z = {0.f, 0.f, 0.f, 0.f};
  const short4_t ones = {(short)0x3F80, (short)0x3F80, (short)0x3F80, (short)0x3F80};

  // --- K staging map (glds direct, 16B granule g ^= row&7) ---
  const int r0 = tid >> 3;
  const int sgk = (tid & 7) ^ (r0 & 7);
  const unsigned short* kg = K + (size_t)r0 * HD + sgk * 8;
  const int kdst = tid * 8;

  // --- V staging map (reg-staged, 8B slot d = w ^ (row&15)) ---
  const int w0 = (tid & 7) * 2;
  const int xa = r0 & 15;
  const int d0 = w0 ^ xa;
  const unsigned short* vsrc = Vt + (size_t)r0 * Sq + w0 * 4;
  const int vdst = r0 * 64 + d0 * 4;

  // --- swizzled read offsets ---
  const int koff0 = (quad ^ lc7) * 8;
  const int koff1 = ((quad | 4) ^ lc7) * 8;
  int voff[4];
#pragma unroll
  for (int s4 = 0; s4 < 4; ++s4) voff[s4] = ((s4 * 4 + quad) ^ lcol) * 4;

  unsigned short* lkc = lk;
  unsigned short* lkn = lk + 4096;
  unsigned short* lvc = lv;
  unsigned short* lvn = lv + 4096;

  int q0w = ti * 128 + wave * 32;       // wave owns rows [q0w, q0w+31]
  int qg0 = q0w + lcol;                 // group0 row
  int qg1 = q0w + 16 + lcol;            // group1 row
  const unsigned short* Qb0 = Q + (size_t)qg0 * HD;
  const unsigned short* Qb1 = Q + (size_t)qg1 * HD;
  short8_t qf0 = *(const short8_t*)(Qb0 + quad * 8);
  short8_t qf1 = *(const short8_t*)(Qb0 + 32 + quad * 8);
  short8_t qf2 = *(const short8_t*)(Qb1 + quad * 8);
  short8_t qf3 = *(const short8_t*)(Qb1 + 32 + quad * 8);
  float mi0 = -INFINITY, mi1 = -INFINITY;
  float4_t l0acc = z, l1acc = z;        // l in o-layout: q = q0w(+16) + quad*4 + r
  float4_t o0[4], o1[4];
#pragma unroll
  for (int f = 0; f < 4; ++f) { o0[f] = z; o1[f] = z; }

  // --- prologue: stage tile 0 ---
  {
    GLOAD_LDS16(kg, lkc + kdst);
    GLOAD_LDS16(kg + (size_t)32 * HD, lkc + 2048 + kdst);
    short4_t a0 = *(const short4_t*)(vsrc);
    short4_t a1 = *(const short4_t*)(vsrc + 4);
    short4_t b0 = *(const short4_t*)(vsrc + (size_t)32 * Sq);
    short4_t b1 = *(const short4_t*)(vsrc + (size_t)32 * Sq + 4);
    *(short4_t*)(lvc + vdst) = a0;
    *(short4_t*)(lvc + (vdst ^ 4)) = a1;
    *(short4_t*)(lvc + vdst + 2048) = b0;
    *(short4_t*)(lvc + (vdst ^ 4) + 2048) = b1;
  }
  __syncthreads();

  int nkt = 2 * ti + 2;
  for (int kt = 0; kt < nkt; ++kt) {
    int key0 = kt * 64;
    bool has_next = (kt + 1 < nkt);
    short4_t va0, va1, vb0, vb1;
    if (has_next) {
      const unsigned short* vs = vsrc + (size_t)(kt + 1) * 64;
      va0 = *(const short4_t*)(vs);
      va1 = *(const short4_t*)(vs + 4);
      vb0 = *(const short4_t*)(vs + (size_t)32 * Sq);
      vb1 = *(const short4_t*)(vs + (size_t)32 * Sq + 4);
      const unsigned short* kgn = kg + (size_t)(kt + 1) * 64 * HD;
      GLOAD_LDS16(kgn, lkn + kdst);
      GLOAD_LDS16(kgn + (size_t)32 * HD, lkn + 2048 + kdst);
    }

    bool active = (key0 <= q0w + 31);   // wave-uniform
    short4_t pf0[4], pf1[4];
    if (active) {
      // --- QK^T: shared kf fragments feed BOTH q-groups ---
      float s0[16], s1[16];
#pragma unroll
      for (int s4 = 0; s4 < 4; ++s4) {
        const unsigned short* kr = lkc + (s4 * 16 + lcol) * 64;
        short8_t kf0 = *(const short8_t*)(kr + koff0);
        short8_t kf1 = *(const short8_t*)(kr + koff1);
        float4_t st0 = z, st1 = z;
        st0 = __builtin_amdgcn_mfma_f32_16x16x32_bf16(kf0, qf0, st0, 0, 0, 0);
        st0 = __builtin_amdgcn_mfma_f32_16x16x32_bf16(kf1, qf1, st0, 0, 0, 0);
        st1 = __builtin_amdgcn_mfma_f32_16x16x32_bf16(kf0, qf2, st1, 0, 0, 0);
        st1 = __builtin_amdgcn_mfma_f32_16x16x32_bf16(kf1, qf3, st1, 0, 0, 0);
#pragma unroll
        for (int r = 0; r < 4; ++r) { s0[s4 * 4 + r] = st0[r]; s1[s4 * 4 + r] = st1[r]; }
      }
      if (key0 + 63 > q0w) {  // diagonal region: mask (per-group exact rows)
#pragma unroll
        for (int s4 = 0; s4 < 4; ++s4)
#pragma unroll
          for (int r = 0; r < 4; ++r) {
            int key = key0 + s4 * 16 + quad * 4 + r;
            if (key > qg0) s0[s4 * 4 + r] = -INFINITY;
            if (key > qg1) s1[s4 * 4 + r] = -INFINITY;
          }
      }

      // --- group 0 softmax (l via MFMA below; no psum) ---
      {
        float ta = m3(s0[0], s0[1], s0[2]);
        float tb = m3(s0[3], s0[4], s0[5]);
        float tc = m3(s0[6], s0[7], s0[8]);
        float td = m3(s0[9], s0[10], s0[11]);
        float te = m3(s0[12], s0[13], s0[14]);
        float tmax = m3(ta, tb, tc);
        tmax = m3(tmax, td, te);
        tmax = fmaxf(tmax, s0[15]);
        tmax = fmaxf(tmax, __shfl_xor(tmax, 16, 64));
        tmax = fmaxf(tmax, __shfl_xor(tmax, 32, 64));
        if (__any(tmax > mi0 + 8.f)) {
          float m_new = fmaxf(mi0, tmax);
          float alpha = exp2_fast(mi0 - m_new);
          mi0 = m_new;
          float at[4];
#pragma unroll
          for (int r = 0; r < 4; ++r) at[r] = __shfl(alpha, quad * 4 + r, 64);
#pragma unroll
          for (int r = 0; r < 4; ++r) l0acc[r] *= at[r];
#pragma unroll
          for (int f = 0; f < 4; ++f)
#pragma unroll
            for (int r = 0; r < 4; ++r) o0[f][r] *= at[r];
        }
#pragma unroll
        for (int s4 = 0; s4 < 4; ++s4) {
          float p0 = exp2_fast(s0[s4 * 4 + 0] - mi0);
          float p1 = exp2_fast(s0[s4 * 4 + 1] - mi0);
          float p2 = exp2_fast(s0[s4 * 4 + 2] - mi0);
          float p3 = exp2_fast(s0[s4 * 4 + 3] - mi0);
          unsigned lo, hi;
          asm("v_cvt_pk_bf16_f32 %0, %1, %2" : "=v"(lo) : "v"(p0), "v"(p1));
          asm("v_cvt_pk_bf16_f32 %0, %1, %2" : "=v"(hi) : "v"(p2), "v"(p3));
          uint2 packed; packed.x = lo; packed.y = hi;
          pf0[s4] = __builtin_bit_cast(short4_t, packed);
        }
      }
      // --- group 1 softmax ---
      {
        float ta = m3(s1[0], s1[1], s1[2]);
        float tb = m3(s1[3], s1[4], s1[5]);
        float tc = m3(s1[6], s1[7], s1[8]);
        float td = m3(s1[9], s1[10], s1[11]);
        float te = m3(s1[12], s1[13], s1[14]);
        float tmax = m3(ta, tb, tc);
        tmax = m3(tmax, td, te);
        tmax = fmaxf(tmax, s1[15]);
        tmax = fmaxf(tmax, __shfl_xor(tmax, 16, 64));
        tmax = fmaxf(tmax, __shfl_xor(tmax, 32, 64));
        if (__any(tmax > mi1 + 8.f)) {
          float m_new = fmaxf(mi1, tmax);
          float alpha = exp2_fast(mi1 - m_new);
          mi1 = m_new;
          float at[4];
#pragma unroll
          for (int r = 0; r < 4; ++r) at[r] = __shfl(alpha, quad * 4 + r, 64);
#pragma unroll
          for (int r = 0; r < 4; ++r) l1acc[r] *= at[r];
#pragma unroll
          for (int f = 0; f < 4; ++f)
#pragma unroll
            for (int r = 0; r < 4; ++r) o1[f][r] *= at[r];
        }
#pragma unroll
        for (int s4 = 0; s4 < 4; ++s4) {
          float p0 = exp2_fast(s1[s4 * 4 + 0] - mi1);
          float p1 = exp2_fast(s1[s4 * 4 + 1] - mi1);
          float p2 = exp2_fast(s1[s4 * 4 + 2] - mi1);
          float p3 = exp2_fast(s1[s4 * 4 + 3] - mi1);
          unsigned lo, hi;
          asm("v_cvt_pk_bf16_f32 %0, %1, %2" : "=v"(lo) : "v"(p0), "v"(p1));
          asm("v_cvt_pk_bf16_f32 %0, %1, %2" : "=v"(hi) : "v"(p2), "v"(p3));
          uint2 packed; packed.x = lo; packed.y = hi;
          pf1[s4] = __builtin_bit_cast(short4_t, packed);
        }
      }
    }

    // --- write next-tile V into alternate buffer (all threads) ---
    if (has_next) {
      *(short4_t*)(lvn + vdst) = va0;
      *(short4_t*)(lvn + (vdst ^ 4)) = va1;
      *(short4_t*)(lvn + vdst + 2048) = vb0;
      *(short4_t*)(lvn + (vdst ^ 4) + 2048) = vb1;
    }

    // --- PV + l-accumulation: shared vf fragments feed BOTH groups ---
    if (active) {
#pragma unroll
      for (int s4 = 0; s4 < 4; ++s4) {
        l0acc = __builtin_amdgcn_mfma_f32_16x16x16bf16_1k(pf0[s4], ones, l0acc, 0, 0, 0);
        l1acc = __builtin_amdgcn_mfma_f32_16x16x16bf16_1k(pf1[s4], ones, l1acc, 0, 0, 0);
      }
#pragma unroll
      for (int f = 0; f < 4; ++f) {
        const unsigned short* vr = lvc + (f * 16 + lcol) * 64;
#pragma unroll
        for (int s4 = 0; s4 < 4; ++s4) {
          short4_t vf = *(const short4_t*)(vr + voff[s4]);
          o0[f] = __builtin_amdgcn_mfma_f32_16x16x16bf16_1k(pf0[s4], vf, o0[f], 0, 0, 0);
          o1[f] = __builtin_amdgcn_mfma_f32_16x16x16bf16_1k(pf1[s4], vf, o1[f], 0, 0, 0);
        }
      }
    }

    __syncthreads();
    unsigned short* t;
    t = lkc; lkc = lkn; lkn = t;
    t = lvc; lvc = lvn; lvn = t;
  }

  // l is already o-indexed (q = q0w(+16) + quad*4 + r): no shfl transpose needed.
  float lt0[4], lt1[4];
#pragma unroll
  for (int r = 0; r < 4; ++r) {
    lt0[r] = 1.f / l0acc[r];
    lt1[r] = 1.f / l1acc[r];
  }
#pragma unroll
  for (int f = 0; f < 4; ++f)
#pragma unroll
    for (int r = 0; r < 4; ++r) {
      int hd = f * 16 + lcol;
      int q0 = q0w + quad * 4 + r;
      int q1 = q0w + 16 + quad * 4 + r;
      ao[((size_t)b * Sq + q0) * (NH * HD) + h * HD + hd] = f2bf(o0[f][r] * lt0[r]);
      ao[((size_t)b * Sq + q1) * (NH * HD) + h * HD + hd] = f2bf(o1[f][r] * lt1[r]);
    }
}

extern "C" void kernel_launch(void* const* d_in, const int* in_sizes, int n_in,
                              void* d_out, int out_size, void* d_ws, size_t ws_size,
                              hipStream_t stream) {
  const float* x = (const float*)d_in[0];
  const float* Wq = (const float*)d_in[1];
  const float* Wk = (const float*)d_in[2];
  const float* Wv = (const float*)d_in[3];
  const float* Wo = (const float*)d_in[4];
  float* out = (float*)d_out;

  char* ws = (char*)d_ws;
  size_t off = 0;
  auto carve = [&](size_t bytes) {
    void* p = ws + off;
    off += (bytes + 255) & ~(size_t)255;
    return p;
  };
  const size_t xe = (size_t)Bz * Sq * Dm;
  const size_t we = (size_t)Dm * Dm;
  unsigned short* xb = (unsigned short*)carve(xe * 2);
  unsigned short* wqT = (unsigned short*)carve(we * 2);
  unsigned short* wkT = (unsigned short*)carve(we * 2);
  unsigned short* wvT = (unsigned short*)carve(we * 2);
  unsigned short* woT = (unsigned short*)carve(we * 2);
  unsigned short* qb = (unsigned short*)carve(xe * 2);
  unsigned short* kb = (unsigned short*)carve(xe * 2);
  unsigned short* vt = (unsigned short*)carve(xe * 2);
  unsigned short* ao = (unsigned short*)carve(xe * 2);
  (void)ws_size;

  cast_x_kernel<<<xe / 4 / 256, 256, 0, stream>>>(x, xb);
  transpose_w_kernel<<<dim3(16, 16, 4), 256, 0, stream>>>(Wq, Wk, Wv, Wo,
                                                          wqT, wkT, wvT, woT);
  gemm_qkv_kernel<<<768, 512, 0, stream>>>(xb, wqT, wkT, wvT, qb, kb, vt);
  attn_kernel<<<dim3(Bz * NH, 16), 256, 0, stream>>>(qb, kb, vt, ao);
  gemm_out_kernel<<<256, 512, 0, stream>>>(ao, woT, out);
}

// Round 11
// 247.214 us; speedup vs baseline: 1.0207x; 1.0207x over previous
//
#include <hip/hip_runtime.h>

// SelfAttention: B=4 S=2048 D=1024 H=16 HD=64, causal, fp32 in/out, bf16 MFMA compute.
// R19->R20: REVERT ones-trick (R19: attn 74.7->80.5, occupancy 27->19 -- the l-MFMA
// chain lengthened the per-wave critical path; attn is latency-chain-bound at ~2
// waves/SIMD, not issue-bound; CU-aggregated VALUBusy had overstated VALU pressure).
// NEW: balanced ti permutation. Grid (64,16)=1024 blocks all co-resident (5/CU by
// LDS); round-robin gives CU k blocks {k',k'+256,k'+512,k'+768} -> ti {15-c,11-c,
// 7-c,3-c} -> per-CU work 80/72/64/56 tile-steps (+18% makespan on the worst CU,
// idle light CUs = occ 27%). Permute y->ti = [15,14,13,12|0,1,2,3|11,10,9,8|4,5,6,7]
// so every residency class sums to 30 (68 steps/CU exactly). Zero-risk index change.
// attn body otherwise byte-identical to R18; GEMMs/cast/transpose unchanged.

typedef __attribute__((ext_vector_type(8))) short short8_t;
typedef __attribute__((ext_vector_type(4))) short short4_t;
typedef __attribute__((ext_vector_type(4))) float float4_t;

constexpr int Bz = 4, Sq = 2048, Dm = 1024, NH = 16, HD = 64;

#define GLOAD_LDS16(g, l)                                                      \
  __builtin_amdgcn_global_load_lds(                                            \
      (const __attribute__((address_space(1))) unsigned int*)(g),              \
      (__attribute__((address_space(3))) unsigned int*)(l), 16, 0, 0)

__device__ __forceinline__ unsigned short f2bf(float f) {
  unsigned u = __builtin_bit_cast(unsigned, f);
  u += 0x7fffu + ((u >> 16) & 1u);
  return (unsigned short)(u >> 16);
}

__device__ __forceinline__ float exp2_fast(float x) {
#if __has_builtin(__builtin_amdgcn_exp2f)
  return __builtin_amdgcn_exp2f(x);
#else
  return exp2f(x);
#endif
}

__device__ __forceinline__ float m3(float a, float b, float c) {
  return fmaxf(fmaxf(a, b), c);  // clang emits v_max3_f32
}

__global__ __launch_bounds__(256) void cast_x_kernel(const float* __restrict__ x,
                                                     unsigned short* __restrict__ xb) {
  size_t i = (size_t)blockIdx.x * 256 + threadIdx.x;
  float4 v = ((const float4*)x)[i];
  ushort4 o;
  o.x = f2bf(v.x); o.y = f2bf(v.y); o.z = f2bf(v.z); o.w = f2bf(v.w);
  ((ushort4*)xb)[i] = o;
}

// All four W [K=1024][N=1024] fp32 -> WT [N][K] bf16 in one launch. grid (16,16,4).
__global__ __launch_bounds__(256) void transpose_w_kernel(
    const float* __restrict__ Wq, const float* __restrict__ Wk,
    const float* __restrict__ Wv, const float* __restrict__ Wo,
    unsigned short* __restrict__ wqT, unsigned short* __restrict__ wkT,
    unsigned short* __restrict__ wvT, unsigned short* __restrict__ woT) {
  __shared__ float tile[64][65];
  int zz = blockIdx.z;
  const float* W = zz == 0 ? Wq : (zz == 1 ? Wk : (zz == 2 ? Wv : Wo));
  unsigned short* WT = zz == 0 ? wqT : (zz == 1 ? wkT : (zz == 2 ? wvT : woT));
  int n0 = blockIdx.x * 64, k0 = blockIdx.y * 64;
  int tx = threadIdx.x & 63, ty = threadIdx.x >> 6;
#pragma unroll
  for (int i = 0; i < 16; ++i) {
    int r = i * 4 + ty;
    tile[r][tx] = W[(size_t)(k0 + r) * Dm + n0 + tx];
  }
  __syncthreads();
#pragma unroll
  for (int i = 0; i < 16; ++i) {
    int r = i * 4 + ty;
    WT[(size_t)(n0 + r) * Dm + k0 + tx] = f2bf(tile[tx][r]);
  }
}

// ---------------- 128x256 8-wave phase-pipelined mainloop ----------------
#define SBAR do { __builtin_amdgcn_sched_barrier(0); __builtin_amdgcn_s_barrier(); } while (0)
#define VMW(n_) asm volatile("s_waitcnt vmcnt(" #n_ ")" ::: "memory")

#define STGA2(buf_, kt_) do {                                                  \
  GLOAD_LDS16(gA + (size_t)lrow * Dm + (kt_) * 64 + csA,                       \
              smA + (buf_) * 8192 + tid * 8);                                  \
  GLOAD_LDS16(gA + (size_t)(lrow + 64) * Dm + (kt_) * 64 + csA,                \
              smA + (buf_) * 8192 + 4096 + tid * 8);                           \
} while (0)
#define STGB4(buf_, kt_) do {                                                  \
  GLOAD_LDS16(gB + (size_t)lrow * Dm + (kt_) * 64 + csA,                       \
              smB + (buf_) * 16384 + tid * 8);                                 \
  GLOAD_LDS16(gB + (size_t)(lrow + 64) * Dm + (kt_) * 64 + csA,                \
              smB + (buf_) * 16384 + 4096 + tid * 8);                          \
  GLOAD_LDS16(gB + (size_t)(lrow + 128) * Dm + (kt_) * 64 + csA,               \
              smB + (buf_) * 16384 + 8192 + tid * 8);                          \
  GLOAD_LDS16(gB + (size_t)(lrow + 192) * Dm + (kt_) * 64 + csA,               \
              smB + (buf_) * 16384 + 12288 + tid * 8);                         \
} while (0)
#define LDA8(buf_) do {                                                        \
  _Pragma("unroll") for (int i_ = 0; i_ < 4; ++i_) {                           \
    const unsigned short* p_ = smA + (buf_) * 8192 + aoff + i_ * 1024;         \
    a[i_][0] = *(const short8_t*)(p_ + csw0);                                  \
    a[i_][1] = *(const short8_t*)(p_ + csw1);                                  \
  }                                                                            \
} while (0)
#define LDB4(dst_, buf_, jh_) do {                                             \
  _Pragma("unroll") for (int j_ = 0; j_ < 2; ++j_) {                           \
    const unsigned short* p_ =                                                 \
        smB + (buf_) * 16384 + boff + ((jh_) * 2 + j_) * 1024;                 \
    dst_[j_][0] = *(const short8_t*)(p_ + csw0);                               \
    dst_[j_][1] = *(const short8_t*)(p_ + csw1);                               \
  }                                                                            \
} while (0)
#define MF16(breg_, joff_) do {                                                \
  __builtin_amdgcn_s_setprio(1);                                               \
  _Pragma("unroll") for (int i_ = 0; i_ < 4; ++i_)                             \
  _Pragma("unroll") for (int j_ = 0; j_ < 2; ++j_) {                           \
    acc[i_][(joff_) + j_] = __builtin_amdgcn_mfma_f32_16x16x32_bf16(           \
        a[i_][0], breg_[j_][0], acc[i_][(joff_) + j_], 0, 0, 0);               \
    acc[i_][(joff_) + j_] = __builtin_amdgcn_mfma_f32_16x16x32_bf16(           \
        a[i_][1], breg_[j_][1], acc[i_][(joff_) + j_], 0, 0, 0);               \
  }                                                                            \
  __builtin_amdgcn_s_setprio(0);                                               \
} while (0)

__device__ __forceinline__ void gemm128x256_mainloop(
    const unsigned short* __restrict__ A, const unsigned short* __restrict__ BT,
    int m0, int n0, unsigned short* smA, unsigned short* smB, float4_t acc[4][4]) {
  const int tid = threadIdx.x;
  const int lane = tid & 63, lr = lane & 15, quad = lane >> 4;
  const int wid = tid >> 6, wm = wid >> 2, wn = wid & 3;
  const int aoff = (wm * 64 + lr) * 64;
  const int boff = (wn * 64 + lr) * 64;
  const int csw0 = (quad ^ (lr & 7)) * 8;
  const int csw1 = csw0 ^ 32;
  const int lrow = tid >> 3;
  const int csA = ((tid & 7) ^ (lrow & 7)) * 8;
  const unsigned short* gA = A + (size_t)m0 * Dm;
  const unsigned short* gB = BT + (size_t)n0 * Dm;

  short8_t a[4][2], bA[2][2], bB[2][2];

  STGA2(0, 0); STGB4(0, 0); STGA2(1, 1);
  VMW(2); SBAR;

#pragma unroll 1
  for (int T = 0; T < 7; ++T) {
    const int t1 = 2 * T + 1, t2 = 2 * T + 2, t3 = 2 * T + 3;
    LDA8(0); LDB4(bA, 0, 0); STGB4(1, t1); SBAR; MF16(bA, 0); SBAR;
    LDB4(bB, 0, 1); STGA2(0, t2); SBAR; MF16(bB, 2); VMW(2); SBAR;
    LDA8(1); LDB4(bA, 1, 0); STGB4(0, t2); SBAR; MF16(bA, 0); SBAR;
    LDB4(bB, 1, 1); STGA2(1, t3); SBAR; MF16(bB, 2); VMW(2); SBAR;
  }
  LDA8(0); LDB4(bA, 0, 0); STGB4(1, 15); SBAR; MF16(bA, 0); SBAR;
  LDB4(bB, 0, 1); SBAR; MF16(bB, 2); VMW(0); SBAR;
  LDA8(1); LDB4(bA, 1, 0); SBAR; MF16(bA, 0); SBAR;
  LDB4(bB, 1, 1); SBAR; MF16(bB, 2);
}

// QKV projections, 128x256 tiles. grid 768 linear (3 exact rounds), XCD cpx=96.
__global__ __launch_bounds__(512, 2) void gemm_qkv_kernel(
    const unsigned short* __restrict__ xb,
    const unsigned short* __restrict__ wqT, const unsigned short* __restrict__ wkT,
    const unsigned short* __restrict__ wvT,
    unsigned short* __restrict__ qb, unsigned short* __restrict__ kb,
    unsigned short* __restrict__ vt) {
  __shared__ unsigned short smA[2 * 8192];
  __shared__ unsigned short smB[2 * 16384];
  int lin = (int)blockIdx.x;
  int logical = (lin & 7) * 96 + (lin >> 3);
  int bx = logical & 3;
  int by = (logical >> 2) & 63;
  int bz = logical >> 8;
  const unsigned short* WT = bz == 0 ? wqT : (bz == 1 ? wkT : wvT);
  unsigned short* outb = bz == 0 ? qb : (bz == 1 ? kb : vt);
  bool isV = bz == 2;
  float qscale = (bz == 0) ? 0.18033688011112042f : 1.0f;
  int m0 = by * 128, n0 = bx * 256;
  float4_t z = {0.f, 0.f, 0.f, 0.f};
  float4_t acc[4][4];
#pragma unroll
  for (int i = 0; i < 4; ++i)
#pragma unroll
    for (int j = 0; j < 4; ++j) acc[i][j] = z;
  gemm128x256_mainloop(xb, WT, m0, n0, smA, smB, acc);

  const int lane = threadIdx.x & 63, lr = lane & 15, quad = lane >> 4;
  const int wid = threadIdx.x >> 6, wm = wid >> 2, wn = wid & 3;
  const int mb = m0 + wm * 64 + quad * 4;
  const int nb = n0 + wn * 64 + lr;
  if (isV) {
#pragma unroll
    for (int ai = 0; ai < 4; ++ai)
#pragma unroll
      for (int bj = 0; bj < 4; ++bj) {
        int m = mb + ai * 16;
        int n = nb + bj * 16;
        int b = m >> 11, s = m & (Sq - 1);
        int h = n >> 6, hd = n & (HD - 1);
        ushort4 pk;
        pk.x = f2bf(acc[ai][bj][0]); pk.y = f2bf(acc[ai][bj][1]);
        pk.z = f2bf(acc[ai][bj][2]); pk.w = f2bf(acc[ai][bj][3]);
        *(ushort4*)(outb + (((size_t)b * NH + h) * HD + hd) * Sq + s) = pk;
      }
  } else {
#pragma unroll
    for (int ai = 0; ai < 4; ++ai)
#pragma unroll
      for (int bj = 0; bj < 4; ++bj)
#pragma unroll
        for (int r = 0; r < 4; ++r) {
          int m = mb + ai * 16 + r;
          int n = nb + bj * 16;
          int b = m >> 11, s = m & (Sq - 1);
          int h = n >> 6, hd = n & (HD - 1);
          outb[(((size_t)b * NH + h) * Sq + s) * HD + hd] = f2bf(acc[ai][bj][r] * qscale);
        }
  }
}

// Output projection: ao_bf16 [8192,1024] @ Wo -> fp32. grid 256 (1 exact round), cpx=32.
__global__ __launch_bounds__(512, 2) void gemm_out_kernel(
    const unsigned short* __restrict__ ao, const unsigned short* __restrict__ woT,
    float* __restrict__ out) {
  __shared__ unsigned short smA[2 * 8192];
  __shared__ unsigned short smB[2 * 16384];
  int lin = (int)blockIdx.x;
  int logical = (lin & 7) * 32 + (lin >> 3);
  int bx = logical & 3;
  int by = logical >> 2;
  int m0 = by * 128, n0 = bx * 256;
  float4_t z = {0.f, 0.f, 0.f, 0.f};
  float4_t acc[4][4];
#pragma unroll
  for (int i = 0; i < 4; ++i)
#pragma unroll
    for (int j = 0; j < 4; ++j) acc[i][j] = z;
  gemm128x256_mainloop(ao, woT, m0, n0, smA, smB, acc);

  const int lane = threadIdx.x & 63, lr = lane & 15, quad = lane >> 4;
  const int wid = threadIdx.x >> 6, wm = wid >> 2, wn = wid & 3;
  const int mb = m0 + wm * 64 + quad * 4;
  const int nb = n0 + wn * 64 + lr;
#pragma unroll
  for (int ai = 0; ai < 4; ++ai)
#pragma unroll
    for (int bj = 0; bj < 4; ++bj)
#pragma unroll
      for (int r = 0; r < 4; ++r) {
        int m = mb + ai * 16 + r;
        int n = nb + bj * 16;
        out[(size_t)m * Dm + n] = acc[ai][bj][r];
      }
}

// Flash attention — grid (B*H, 16), 128-row q-tile per block, 4 waves x 32 q-rows.
// ti via balanced permutation (each co-residency class sums to 30 -> 68 steps/CU).
// K/V fragments shared by both 16-row groups per wave. Double-buffered K (glds,
// 16B XOR) and V (reg-staged, 8B-slot XOR ^row&15). Wave-uniform masked-tile skip.
__global__ __launch_bounds__(256) void attn_kernel(
    const unsigned short* __restrict__ qbuf, const unsigned short* __restrict__ kbuf,
    const unsigned short* __restrict__ vtbuf, unsigned short* __restrict__ ao) {
  __shared__ unsigned short lk[2 * 64 * 64];
  __shared__ unsigned short lv[2 * 64 * 64];
  int tid = threadIdx.x;
  int bh = blockIdx.x;
  // Balanced y->ti: [15,14,13,12 | 0,1,2,3 | 11,10,9,8 | 4,5,6,7]
  int y = (int)blockIdx.y;
  int yq = y >> 2, yr = y & 3;
  int ti = (yq == 0) ? (15 - yr) : (yq == 1) ? yr : (yq == 2) ? (11 - yr) : (4 + yr);
  int wave = tid >> 6, lane = tid & 63;
  int lcol = lane & 15, quad = lane >> 4;
  int lc7 = lcol & 7;
  const unsigned short* Q = qbuf + (size_t)bh * Sq * HD;
  const unsigned short* K = kbuf + (size_t)bh * Sq * HD;
  const unsigned short* Vt = vtbuf + (size_t)bh * HD * Sq;
  int b = bh >> 4, h = bh & 15;
  float4_t z = {0.f, 0.f, 0.f, 0.f};

  // --- K staging map (glds direct, 16B granule g ^= row&7) ---
  const int r0 = tid >> 3;
  const int sgk = (tid & 7) ^ (r0 & 7);
  const unsigned short* kg = K + (size_t)r0 * HD + sgk * 8;
  const int kdst = tid * 8;

  // --- V staging map (reg-staged, 8B slot d = w ^ (row&15)) ---
  const int w0 = (tid & 7) * 2;
  const int xa = r0 & 15;
  const int d0 = w0 ^ xa;
  const unsigned short* vsrc = Vt + (size_t)r0 * Sq + w0 * 4;
  const int vdst = r0 * 64 + d0 * 4;

  // --- swizzled read offsets ---
  const int koff0 = (quad ^ lc7) * 8;
  const int koff1 = ((quad | 4) ^ lc7) * 8;
  int voff[4];
#pragma unroll
  for (int s4 = 0; s4 < 4; ++s4) voff[s4] = ((s4 * 4 + quad) ^ lcol) * 4;

  unsigned short* lkc = lk;
  unsigned short* lkn = lk + 4096;
  unsigned short* lvc = lv;
  unsigned short* lvn = lv + 4096;

  int q0w = ti * 128 + wave * 32;       // wave owns rows [q0w, q0w+31]
  int qg0 = q0w + lcol;                 // group0 row
  int qg1 = q0w + 16 + lcol;            // group1 row
  const unsigned short* Qb0 = Q + (size_t)qg0 * HD;
  const unsigned short* Qb1 = Q + (size_t)qg1 * HD;
  short8_t qf0 = *(const short8_t*)(Qb0 + quad * 8);
  short8_t qf1 = *(const short8_t*)(Qb0 + 32 + quad * 8);
  short8_t qf2 = *(const short8_t*)(Qb1 + quad * 8);
  short8_t qf3 = *(const short8_t*)(Qb1 + 32 + quad * 8);
  float mi0 = -INFINITY, li0 = 0.f;
  float mi1 = -INFINITY, li1 = 0.f;
  float4_t o0[4], o1[4];
#pragma unroll
  for (int f = 0; f < 4; ++f) { o0[f] = z; o1[f] = z; }

  // --- prologue: stage tile 0 ---
  {
    GLOAD_LDS16(kg, lkc + kdst);
    GLOAD_LDS16(kg + (size_t)32 * HD, lkc + 2048 + kdst);
    short4_t a0 = *(const short4_t*)(vsrc);
    short4_t a1 = *(const short4_t*)(vsrc + 4);
    short4_t b0 = *(const short4_t*)(vsrc + (size_t)32 * Sq);
    short4_t b1 = *(const short4_t*)(vsrc + (size_t)32 * Sq + 4);
    *(short4_t*)(lvc + vdst) = a0;
    *(short4_t*)(lvc + (vdst ^ 4)) = a1;
    *(short4_t*)(lvc + vdst + 2048) = b0;
    *(short4_t*)(lvc + (vdst ^ 4) + 2048) = b1;
  }
  __syncthreads();

  int nkt = 2 * ti + 2;
  for (int kt = 0; kt < nkt; ++kt) {
    int key0 = kt * 64;
    bool has_next = (kt + 1 < nkt);
    short4_t va0, va1, vb0, vb1;
    if (has_next) {
      const unsigned short* vs = vsrc + (size_t)(kt + 1) * 64;
      va0 = *(const short4_t*)(vs);
      va1 = *(const short4_t*)(vs + 4);
      vb0 = *(const short4_t*)(vs + (size_t)32 * Sq);
      vb1 = *(const short4_t*)(vs + (size_t)32 * Sq + 4);
      const unsigned short* kgn = kg + (size_t)(kt + 1) * 64 * HD;
      GLOAD_LDS16(kgn, lkn + kdst);
      GLOAD_LDS16(kgn + (size_t)32 * HD, lkn + 2048 + kdst);
    }

    bool active = (key0 <= q0w + 31);   // wave-uniform
    short4_t pf0[4], pf1[4];
    if (active) {
      // --- QK^T: shared kf fragments feed BOTH q-groups ---
      float s0[16], s1[16];
#pragma unroll
      for (int s4 = 0; s4 < 4; ++s4) {
        const unsigned short* kr = lkc + (s4 * 16 + lcol) * 64;
        short8_t kf0 = *(const short8_t*)(kr + koff0);
        short8_t kf1 = *(const short8_t*)(kr + koff1);
        float4_t st0 = z, st1 = z;
        st0 = __builtin_amdgcn_mfma_f32_16x16x32_bf16(kf0, qf0, st0, 0, 0, 0);
        st0 = __builtin_amdgcn_mfma_f32_16x16x32_bf16(kf1, qf1, st0, 0, 0, 0);
        st1 = __builtin_amdgcn_mfma_f32_16x16x32_bf16(kf0, qf2, st1, 0, 0, 0);
        st1 = __builtin_amdgcn_mfma_f32_16x16x32_bf16(kf1, qf3, st1, 0, 0, 0);
#pragma unroll
        for (int r = 0; r < 4; ++r) { s0[s4 * 4 + r] = st0[r]; s1[s4 * 4 + r] = st1[r]; }
      }
      if (key0 + 63 > q0w) {  // diagonal region: mask (per-group exact rows)
#pragma unroll
        for (int s4 = 0; s4 < 4; ++s4)
#pragma unroll
          for (int r = 0; r < 4; ++r) {
            int key = key0 + s4 * 16 + quad * 4 + r;
            if (key > qg0) s0[s4 * 4 + r] = -INFINITY;
            if (key > qg1) s1[s4 * 4 + r] = -INFINITY;
          }
      }

      // --- group 0 softmax ---
      {
        float ta = m3(s0[0], s0[1], s0[2]);
        float tb = m3(s0[3], s0[4], s0[5]);
        float tc = m3(s0[6], s0[7], s0[8]);
        float td = m3(s0[9], s0[10], s0[11]);
        float te = m3(s0[12], s0[13], s0[14]);
        float tmax = m3(ta, tb, tc);
        tmax = m3(tmax, td, te);
        tmax = fmaxf(tmax, s0[15]);
        tmax = fmaxf(tmax, __shfl_xor(tmax, 16, 64));
        tmax = fmaxf(tmax, __shfl_xor(tmax, 32, 64));
        if (__any(tmax > mi0 + 8.f)) {
          float m_new = fmaxf(mi0, tmax);
          float alpha = exp2_fast(mi0 - m_new);
          li0 *= alpha;
          mi0 = m_new;
          float at[4];
#pragma unroll
          for (int r = 0; r < 4; ++r) at[r] = __shfl(alpha, quad * 4 + r, 64);
#pragma unroll
          for (int f = 0; f < 4; ++f)
#pragma unroll
            for (int r = 0; r < 4; ++r) o0[f][r] *= at[r];
        }
        float psum = 0.f;
#pragma unroll
        for (int s4 = 0; s4 < 4; ++s4) {
          float p0 = exp2_fast(s0[s4 * 4 + 0] - mi0);
          float p1 = exp2_fast(s0[s4 * 4 + 1] - mi0);
          float p2 = exp2_fast(s0[s4 * 4 + 2] - mi0);
          float p3 = exp2_fast(s0[s4 * 4 + 3] - mi0);
          psum += (p0 + p1) + (p2 + p3);
          unsigned lo, hi;
          asm("v_cvt_pk_bf16_f32 %0, %1, %2" : "=v"(lo) : "v"(p0), "v"(p1));
          asm("v_cvt_pk_bf16_f32 %0, %1, %2" : "=v"(hi) : "v"(p2), "v"(p3));
          uint2 packed; packed.x = lo; packed.y = hi;
          pf0[s4] = __builtin_bit_cast(short4_t, packed);
        }
        psum += __shfl_xor(psum, 16, 64);
        psum += __shfl_xor(psum, 32, 64);
        li0 += psum;
      }
      // --- group 1 softmax ---
      {
        float ta = m3(s1[0], s1[1], s1[2]);
        float tb = m3(s1[3], s1[4], s1[5]);
        float tc = m3(s1[6], s1[7], s1[8]);
        float td = m3(s1[9], s1[10], s1[11]);
        float te = m3(s1[12], s1[13], s1[14]);
        float tmax = m3(ta, tb, tc);
        tmax = m3(tmax, td, te);
        tmax = fmaxf(tmax, s1[15]);
        tmax = fmaxf(tmax, __shfl_xor(tmax, 16, 64));
        tmax = fmaxf(tmax, __shfl_xor(tmax, 32, 64));
        if (__any(tmax > mi1 + 8.f)) {
          float m_new = fmaxf(mi1, tmax);
          float alpha = exp2_fast(mi1 - m_new);
          li1 *= alpha;
          mi1 = m_new;
          float at[4];
#pragma unroll
          for (int r = 0; r < 4; ++r) at[r] = __shfl(alpha, quad * 4 + r, 64);
#pragma unroll
          for (int f = 0; f < 4; ++f)
#pragma unroll
            for (int r = 0; r < 4; ++r) o1[f][r] *= at[r];
        }
        float psum = 0.f;
#pragma unroll
        for (int s4 = 0; s4 < 4; ++s4) {
          float p0 = exp2_fast(s1[s4 * 4 + 0] - mi1);
          float p1 = exp2_fast(s1[s4 * 4 + 1] - mi1);
          float p2 = exp2_fast(s1[s4 * 4 + 2] - mi1);
          float p3 = exp2_fast(s1[s4 * 4 + 3] - mi1);
          psum += (p0 + p1) + (p2 + p3);
          unsigned lo, hi;
          asm("v_cvt_pk_bf16_f32 %0, %1, %2" : "=v"(lo) : "v"(p0), "v"(p1));
          asm("v_cvt_pk_bf16_f32 %0, %1, %2" : "=v"(hi) : "v"(p2), "v"(p3));
          uint2 packed; packed.x = lo; packed.y = hi;
          pf1[s4] = __builtin_bit_cast(short4_t, packed);
        }
        psum += __shfl_xor(psum, 16, 64);
        psum += __shfl_xor(psum, 32, 64);
        li1 += psum;
      }
    }

    // --- write next-tile V into alternate buffer (all threads) ---
    if (has_next) {
      *(short4_t*)(lvn + vdst) = va0;
      *(short4_t*)(lvn + (vdst ^ 4)) = va1;
      *(short4_t*)(lvn + vdst + 2048) = vb0;
      *(short4_t*)(lvn + (vdst ^ 4) + 2048) = vb1;
    }

    // --- PV: shared vf fragments feed BOTH groups ---
    if (active) {
#pragma unroll
      for (int f = 0; f < 4; ++f) {
        const unsigned short* vr = lvc + (f * 16 + lcol) * 64;
#pragma unroll
        for (int s4 = 0; s4 < 4; ++s4) {
          short4_t vf = *(const short4_t*)(vr + voff[s4]);
          o0[f] = __builtin_amdgcn_mfma_f32_16x16x16bf16_1k(pf0[s4], vf, o0[f], 0, 0, 0);
          o1[f] = __builtin_amdgcn_mfma_f32_16x16x16bf16_1k(pf1[s4], vf, o1[f], 0, 0, 0);
        }
      }
    }

    __syncthreads();
    unsigned short* t;
    t = lkc; lkc = lkn; lkn = t;
    t = lvc; lvc = lvn; lvn = t;
  }

  float lt0[4], lt1[4];
#pragma unroll
  for (int r = 0; r < 4; ++r) {
    lt0[r] = 1.f / __shfl(li0, quad * 4 + r, 64);
    lt1[r] = 1.f / __shfl(li1, quad * 4 + r, 64);
  }
#pragma unroll
  for (int f = 0; f < 4; ++f)
#pragma unroll
    for (int r = 0; r < 4; ++r) {
      int hd = f * 16 + lcol;
      int q0 = q0w + quad * 4 + r;
      int q1 = q0w + 16 + quad * 4 + r;
      ao[((size_t)b * Sq + q0) * (NH * HD) + h * HD + hd] = f2bf(o0[f][r] * lt0[r]);
      ao[((size_t)b * Sq + q1) * (NH * HD) + h * HD + hd] = f2bf(o1[f][r] * lt1[r]);
    }
}

extern "C" void kernel_launch(void* const* d_in, const int* in_sizes, int n_in,
                              void* d_out, int out_size, void* d_ws, size_t ws_size,
                              hipStream_t stream) {
  const float* x = (const float*)d_in[0];
  const float* Wq = (const float*)d_in[1];
  const float* Wk = (const float*)d_in[2];
  const float* Wv = (const float*)d_in[3];
  const float* Wo = (const float*)d_in[4];
  float* out = (float*)d_out;

  char* ws = (char*)d_ws;
  size_t off = 0;
  auto carve = [&](size_t bytes) {
    void* p = ws + off;
    off += (bytes + 255) & ~(size_t)255;
    return p;
  };
  const size_t xe = (size_t)Bz * Sq * Dm;
  const size_t we = (size_t)Dm * Dm;
  unsigned short* xb = (unsigned short*)carve(xe * 2);
  unsigned short* wqT = (unsigned short*)carve(we * 2);
  unsigned short* wkT = (unsigned short*)carve(we * 2);
  unsigned short* wvT = (unsigned short*)carve(we * 2);
  unsigned short* woT = (unsigned short*)carve(we * 2);
  unsigned short* qb = (unsigned short*)carve(xe * 2);
  unsigned short* kb = (unsigned short*)carve(xe * 2);
  unsigned short* vt = (unsigned short*)carve(xe * 2);
  unsigned short* ao = (unsigned short*)carve(xe * 2);
  (void)ws_size;

  cast_x_kernel<<<xe / 4 / 256, 256, 0, stream>>>(x, xb);
  transpose_w_kernel<<<dim3(16, 16, 4), 256, 0, stream>>>(Wq, Wk, Wv, Wo,
                                                          wqT, wkT, wvT, woT);
  gemm_qkv_kernel<<<768, 512, 0, stream>>>(xb, wqT, wkT, wvT, qb, kb, vt);
  attn_kernel<<<dim3(Bz * NH, 16), 256, 0, stream>>>(qb, kb, vt, ao);
  gemm_out_kernel<<<256, 512, 0, stream>>>(ao, woT, out);
}